// Round 1
// baseline (1522.269 us; speedup 1.0000x reference)
//
#include <hip/hip_runtime.h>

#define NN 100000
#define NE 1280000
#define D  64

// ---------------------------------------------------------------------------
// 1) in-degree counts: one int atomic per edge
// ---------------------------------------------------------------------------
__global__ __launch_bounds__(256) void count_kernel(const int* __restrict__ dst,
                                                    int* __restrict__ cnt) {
    int e = blockIdx.x * blockDim.x + threadIdx.x;
    if (e < NE) atomicAdd(&cnt[dst[e]], 1);
}

// ---------------------------------------------------------------------------
// 2) scatter-add of source features into agg[dst]
//    thread = (edge, feature); one 64-lane wave handles one edge:
//    gather is a coalesced 256B read, scatter is 64 contiguous fp32 atomics.
// ---------------------------------------------------------------------------
__global__ __launch_bounds__(256) void scatter_kernel(const float* __restrict__ feat,
                                                      const int* __restrict__ src,
                                                      const int* __restrict__ dst,
                                                      float* __restrict__ agg) {
    int gid = blockIdx.x * blockDim.x + threadIdx.x;   // < 81.92M, fits int32
    int e = gid >> 6;
    int f = gid & 63;
    if (e < NE) {
        int s = src[e];
        int d = dst[e];
        atomicAdd(&agg[(size_t)d * D + f], feat[(size_t)s * D + f]);
    }
}

// ---------------------------------------------------------------------------
// 3) fused combine: out = [relu]( W_l @ (agg/max(cnt,1)) + b + W_r @ xin )
//    4 nodes per 256-thread block; W_l, W_r transposed into LDS so the
//    inner-loop read Wl[k*64+f] is contiguous across lanes (conflict-free).
//    NOTE: xin and out may alias (layer-2 in-place) -> rows are staged into
//    LDS behind a barrier before any write; no __restrict__ on xin/out.
// ---------------------------------------------------------------------------
__global__ __launch_bounds__(256) void combine_kernel(const float* __restrict__ agg,
                                                      const int* __restrict__ cnt,
                                                      const float* xin,
                                                      const float* __restrict__ W_l,
                                                      const float* __restrict__ b,
                                                      const float* __restrict__ W_r,
                                                      float* out,
                                                      int do_relu) {
    __shared__ float Wl[D * D];   // transposed: Wl[k*64 + f] = W_l[f][k]
    __shared__ float Wr[D * D];
    __shared__ float xr[4][D];
    __shared__ float mr[4][D];

    int tid = threadIdx.x;
    for (int idx = tid; idx < D * D; idx += 256) {
        int f = idx >> 6;        // output row of W
        int k = idx & 63;        // input col of W
        Wl[k * D + f] = W_l[idx];
        Wr[k * D + f] = W_r[idx];
    }
    __syncthreads();

    int n = tid >> 6;            // 0..3  node slot within block
    int f = tid & 63;            // output feature
    int node = blockIdx.x * 4 + n;

    if (node < NN) {
        float c   = (float)cnt[node];
        float inv = 1.0f / fmaxf(c, 1.0f);
        xr[n][f] = xin[(size_t)node * D + f];
        mr[n][f] = agg[(size_t)node * D + f] * inv;
    }
    __syncthreads();

    if (node < NN) {
        float acc = b[f];
        #pragma unroll
        for (int k = 0; k < D; ++k) {
            acc += Wl[k * D + f] * mr[n][k] + Wr[k * D + f] * xr[n][k];
        }
        if (do_relu) acc = fmaxf(acc, 0.0f);
        out[(size_t)node * D + f] = acc;
    }
}

// ---------------------------------------------------------------------------
extern "C" void kernel_launch(void* const* d_in, const int* in_sizes, int n_in,
                              void* d_out, int out_size, void* d_ws, size_t ws_size,
                              hipStream_t stream) {
    const float* x   = (const float*)d_in[0];
    const int*   ei  = (const int*)d_in[1];     // [2, NE] int32
    const float* W1l = (const float*)d_in[2];
    const float* b1  = (const float*)d_in[3];
    const float* W1r = (const float*)d_in[4];
    const float* W2l = (const float*)d_in[5];
    const float* b2  = (const float*)d_in[6];
    const float* W2r = (const float*)d_in[7];
    float*       out = (float*)d_out;

    const int* src = ei;
    const int* dst = ei + NE;

    float* agg = (float*)d_ws;                              // NN*D fp32 = 25.6 MB
    int*   cnt = (int*)((char*)d_ws + (size_t)NN * D * 4);  // NN int32 = 0.4 MB

    const size_t agg_bytes = (size_t)NN * D * 4;
    const size_t cnt_bytes = (size_t)NN * 4;

    // zero agg + cnt (contiguous)
    hipMemsetAsync(d_ws, 0, agg_bytes + cnt_bytes, stream);

    // in-degree (same for both layers)
    count_kernel<<<(NE + 255) / 256, 256, 0, stream>>>(dst, cnt);

    // ---- layer 1 ----
    scatter_kernel<<<(NE * 64) / 256, 256, 0, stream>>>(x, src, dst, agg);
    combine_kernel<<<(NN + 3) / 4, 256, 0, stream>>>(agg, cnt, x, W1l, b1, W1r, out, 1);

    // ---- layer 2 (h lives in d_out; combine is safely in-place) ----
    hipMemsetAsync(agg, 0, agg_bytes, stream);
    scatter_kernel<<<(NE * 64) / 256, 256, 0, stream>>>(out, src, dst, agg);
    combine_kernel<<<(NN + 3) / 4, 256, 0, stream>>>(agg, cnt, out, W2l, b2, W2r, out, 0);
}

// Round 2
// 503.026 us; speedup vs baseline: 3.0262x; 3.0262x over previous
//
#include <hip/hip_runtime.h>

#define NN 100000
#define NE 1280000
#define D  64
#define NPART ((NN + 255) / 256)   // 391 scan partials

// ---------------------------------------------------------------------------
// 1) in-degree counts
// ---------------------------------------------------------------------------
__global__ __launch_bounds__(256) void count_kernel(const int* __restrict__ dst,
                                                    int* __restrict__ cnt) {
    int e = blockIdx.x * blockDim.x + threadIdx.x;
    if (e < NE) atomicAdd(&cnt[dst[e]], 1);
}

// ---------------------------------------------------------------------------
// 2) exclusive scan of cnt -> offs  (3-kernel: block scan, partial scan, add)
// ---------------------------------------------------------------------------
__global__ __launch_bounds__(256) void scanA(const int* __restrict__ cnt,
                                             int* __restrict__ offs,
                                             int* __restrict__ partial) {
    __shared__ int buf[256];
    int i = blockIdx.x * 256 + threadIdx.x;
    int v = (i < NN) ? cnt[i] : 0;
    buf[threadIdx.x] = v;
    __syncthreads();
    for (int d = 1; d < 256; d <<= 1) {
        int t = (threadIdx.x >= d) ? buf[threadIdx.x - d] : 0;
        __syncthreads();
        buf[threadIdx.x] += t;
        __syncthreads();
    }
    if (i < NN) offs[i] = buf[threadIdx.x] - v;          // exclusive
    if (threadIdx.x == 255) partial[blockIdx.x] = buf[255];
}

__global__ __launch_bounds__(512) void scanB(int* __restrict__ partial) {
    __shared__ int buf[512];
    int v = (threadIdx.x < NPART) ? partial[threadIdx.x] : 0;
    buf[threadIdx.x] = v;
    __syncthreads();
    for (int d = 1; d < 512; d <<= 1) {
        int t = (threadIdx.x >= d) ? buf[threadIdx.x - d] : 0;
        __syncthreads();
        buf[threadIdx.x] += t;
        __syncthreads();
    }
    if (threadIdx.x < NPART) partial[threadIdx.x] = buf[threadIdx.x] - v;  // exclusive
}

__global__ __launch_bounds__(256) void scanC(int* __restrict__ offs,
                                             const int* __restrict__ partial) {
    int i = blockIdx.x * 256 + threadIdx.x;
    if (i < NN) offs[i] += partial[blockIdx.x];
}

// ---------------------------------------------------------------------------
// 3) bucket edges into CSR col array
// ---------------------------------------------------------------------------
__global__ __launch_bounds__(256) void bucket_kernel(const int* __restrict__ src,
                                                     const int* __restrict__ dst,
                                                     const int* __restrict__ offs,
                                                     int* __restrict__ cursor,
                                                     int* __restrict__ col) {
    int e = blockIdx.x * 256 + threadIdx.x;
    if (e < NE) {
        int d = dst[e];
        int pos = offs[d] + atomicAdd(&cursor[d], 1);
        col[pos] = src[e];
    }
}

// ---------------------------------------------------------------------------
// 4) fused gather-aggregate + SAGE combine.
//    One wave per node (lane = feature). Edge list via wave-uniform scalar
//    loads; neighbor rows are coalesced 256B loads summed in registers.
//    W_l/W_r rows live in 128 VGPRs per lane (loaded once per wave,
//    amortized over ~12 nodes by grid-stride). Broadcast of mean[k]/x[k]
//    via v_readlane -> SGPR -> v_fmac(v,s,v). No LDS, no atomics.
// ---------------------------------------------------------------------------
__device__ __forceinline__ float bcast(float v, int k) {
    return __uint_as_float(__builtin_amdgcn_readlane(__float_as_uint(v), k));
}

__global__ __launch_bounds__(256) void sage_fused(const float* __restrict__ xin,
                                                  const int* __restrict__ col,
                                                  const int* __restrict__ offs,
                                                  const int* __restrict__ cnt,
                                                  const float* __restrict__ W_l,
                                                  const float* __restrict__ b,
                                                  const float* __restrict__ W_r,
                                                  float* __restrict__ out,
                                                  int do_relu) {
    const int lane = threadIdx.x & 63;
    const int wslot = __builtin_amdgcn_readfirstlane(threadIdx.x >> 6);

    // per-lane weight rows: W[f=lane][k], k = 0..63
    float wl[D], wr[D];
    {
        const float4* wl4 = (const float4*)(W_l + (size_t)lane * D);
        const float4* wr4 = (const float4*)(W_r + (size_t)lane * D);
        #pragma unroll
        for (int k4 = 0; k4 < D / 4; ++k4) {
            float4 a = wl4[k4];
            wl[k4 * 4 + 0] = a.x; wl[k4 * 4 + 1] = a.y;
            wl[k4 * 4 + 2] = a.z; wl[k4 * 4 + 3] = a.w;
            float4 c = wr4[k4];
            wr[k4 * 4 + 0] = c.x; wr[k4 * 4 + 1] = c.y;
            wr[k4 * 4 + 2] = c.z; wr[k4 * 4 + 3] = c.w;
        }
    }
    const float bias = b[lane];

    const int nwaves = gridDim.x * 4;
    int node = blockIdx.x * 4 + wslot;

    for (; node < NN; node += nwaves) {
        const int un  = __builtin_amdgcn_readfirstlane(node);
        const int off = offs[un];          // scalar loads (un uniform)
        const int deg = cnt[un];

        float s0 = 0.f, s1 = 0.f, s2 = 0.f, s3 = 0.f;
        int j = 0;
        for (; j + 4 <= deg; j += 4) {
            int e0 = col[off + j + 0];
            int e1 = col[off + j + 1];
            int e2 = col[off + j + 2];
            int e3 = col[off + j + 3];
            s0 += xin[(size_t)e0 * D + lane];
            s1 += xin[(size_t)e1 * D + lane];
            s2 += xin[(size_t)e2 * D + lane];
            s3 += xin[(size_t)e3 * D + lane];
        }
        for (; j < deg; ++j) {
            int e0 = col[off + j];
            s0 += xin[(size_t)e0 * D + lane];
        }
        const float inv  = 1.0f / (float)(deg > 0 ? deg : 1);
        const float mean = ((s0 + s1) + (s2 + s3)) * inv;
        const float xv   = xin[(size_t)un * D + lane];

        float acc = bias;
        #pragma unroll
        for (int k = 0; k < D; ++k) {
            acc += wl[k] * bcast(mean, k);
            acc += wr[k] * bcast(xv, k);
        }
        if (do_relu) acc = fmaxf(acc, 0.0f);
        out[(size_t)un * D + lane] = acc;
    }
}

// ---------------------------------------------------------------------------
extern "C" void kernel_launch(void* const* d_in, const int* in_sizes, int n_in,
                              void* d_out, int out_size, void* d_ws, size_t ws_size,
                              hipStream_t stream) {
    const float* x   = (const float*)d_in[0];
    const int*   ei  = (const int*)d_in[1];     // [2, NE] int32
    const float* W1l = (const float*)d_in[2];
    const float* b1  = (const float*)d_in[3];
    const float* W1r = (const float*)d_in[4];
    const float* W2l = (const float*)d_in[5];
    const float* b2  = (const float*)d_in[6];
    const float* W2r = (const float*)d_in[7];
    float*       out = (float*)d_out;

    const int* src = ei;
    const int* dst = ei + NE;

    // workspace layout (~31.9 MB)
    char* p = (char*)d_ws;
    float* h      = (float*)p;                 p += (size_t)NN * D * 4;  // 25.6 MB
    int*   col    = (int*)p;                   p += (size_t)NE * 4;      //  5.12 MB
    int*   cnt    = (int*)p;                   p += (size_t)NN * 4;      //  0.4 MB
    int*   cursor = (int*)p;                   p += (size_t)NN * 4;      //  0.4 MB
    int*   offs   = (int*)p;                   p += (size_t)NN * 4;      //  0.4 MB
    int*   part   = (int*)p;

    // zero cnt + cursor (contiguous)
    hipMemsetAsync(cnt, 0, (size_t)NN * 4 * 2, stream);

    // ---- CSR build (shared by both layers) ----
    count_kernel<<<(NE + 255) / 256, 256, 0, stream>>>(dst, cnt);
    scanA<<<NPART, 256, 0, stream>>>(cnt, offs, part);
    scanB<<<1, 512, 0, stream>>>(part);
    scanC<<<NPART, 256, 0, stream>>>(offs, part);
    bucket_kernel<<<(NE + 255) / 256, 256, 0, stream>>>(src, dst, offs, cursor, col);

    // ---- layer 1: x -> h (relu) ----
    sage_fused<<<2048, 256, 0, stream>>>(x, col, offs, cnt, W1l, b1, W1r, h, 1);

    // ---- layer 2: h -> out ----
    sage_fused<<<2048, 256, 0, stream>>>(h, col, offs, cnt, W2l, b2, W2r, out, 0);
}

// Round 3
// 357.590 us; speedup vs baseline: 4.2570x; 1.4067x over previous
//
#include <hip/hip_runtime.h>

#define NN 100000
#define NE 1280000
#define D  64
#define NPART ((NN + 255) / 256)   // 391 scan partials

typedef unsigned int  uint;
typedef unsigned short ushort;
typedef __attribute__((ext_vector_type(8))) short short8v;   // 8 bf16 (4 VGPR)
typedef __attribute__((ext_vector_type(4))) float f32x4;

// float -> bf16 round-to-nearest-even
__device__ __forceinline__ ushort f2bf(float f) {
    uint u = __float_as_uint(f);
    uint r = (u + 0x7fffu + ((u >> 16) & 1u)) >> 16;
    return (ushort)r;
}
__device__ __forceinline__ float bf2f(ushort h) {
    return __uint_as_float(((uint)h) << 16);
}
__device__ __forceinline__ float bfhi_f(uint w) { return __uint_as_float(w & 0xffff0000u); }
__device__ __forceinline__ float bflo_f(uint w) { return __uint_as_float(w << 16); }

// ---------------------------------------------------------------------------
// CSR build
// ---------------------------------------------------------------------------
__global__ __launch_bounds__(256) void count_kernel(const int* __restrict__ dst,
                                                    int* __restrict__ cnt) {
    int e = blockIdx.x * 256 + threadIdx.x;
    if (e < NE) atomicAdd(&cnt[dst[e]], 1);
}

__global__ __launch_bounds__(256) void scanA(const int* __restrict__ cnt,
                                             int* __restrict__ offs,
                                             int* __restrict__ partial) {
    __shared__ int buf[256];
    int i = blockIdx.x * 256 + threadIdx.x;
    int v = (i < NN) ? cnt[i] : 0;
    buf[threadIdx.x] = v;
    __syncthreads();
    for (int d = 1; d < 256; d <<= 1) {
        int t = (threadIdx.x >= d) ? buf[threadIdx.x - d] : 0;
        __syncthreads();
        buf[threadIdx.x] += t;
        __syncthreads();
    }
    if (i < NN) offs[i] = buf[threadIdx.x] - v;          // exclusive (block-local)
    if (threadIdx.x == 255) partial[blockIdx.x] = buf[255];
}

__global__ __launch_bounds__(512) void scanB(int* __restrict__ partial) {
    __shared__ int buf[512];
    int v = (threadIdx.x < NPART) ? partial[threadIdx.x] : 0;
    buf[threadIdx.x] = v;
    __syncthreads();
    for (int d = 1; d < 512; d <<= 1) {
        int t = (threadIdx.x >= d) ? buf[threadIdx.x - d] : 0;
        __syncthreads();
        buf[threadIdx.x] += t;
        __syncthreads();
    }
    if (threadIdx.x < NPART) partial[threadIdx.x] = buf[threadIdx.x] - v;  // exclusive
}

__global__ __launch_bounds__(256) void scanC(int* __restrict__ offs,
                                             const int* __restrict__ partial) {
    int i = blockIdx.x * 256 + threadIdx.x;
    if (i < NN) offs[i] += partial[blockIdx.x];
}

// bucket; consumes cnt (atomicSub -> ends at 0). Neighbor order within a
// segment is reversed — irrelevant for a sum.
__global__ __launch_bounds__(256) void bucket_kernel(const int* __restrict__ src,
                                                     const int* __restrict__ dst,
                                                     const int* __restrict__ offs,
                                                     int* __restrict__ cnt,
                                                     int* __restrict__ col) {
    int e = blockIdx.x * 256 + threadIdx.x;
    if (e < NE) {
        int d = dst[e];
        int pos = offs[d] + atomicSub(&cnt[d], 1) - 1;
        col[pos] = src[e];
    }
}

// ---------------------------------------------------------------------------
// prep: x (fp32) -> xb (bf16 pairs packed in uint)
// ---------------------------------------------------------------------------
__global__ __launch_bounds__(256) void prep_x(const float* __restrict__ x,
                                              uint* __restrict__ xb) {
    int i = blockIdx.x * 256 + threadIdx.x;      // uint index; total NN*32
    if (i < NN * 32) {
        float2 v = ((const float2*)x)[i];
        xb[i] = (uint)f2bf(v.x) | ((uint)f2bf(v.y) << 16);
    }
}

// prep: 4 weight matrices fp32 -> hi/lo bf16 (error compensation split)
__global__ __launch_bounds__(256) void prep_w(const float* __restrict__ w0,
                                              const float* __restrict__ w1,
                                              const float* __restrict__ w2,
                                              const float* __restrict__ w3,
                                              ushort* __restrict__ hi,
                                              ushort* __restrict__ lo) {
    int g = blockIdx.x * 256 + threadIdx.x;      // 4*4096
    if (g < 4 * 4096) {
        int m = g >> 12;
        const float* src = (m == 0) ? w0 : (m == 1) ? w1 : (m == 2) ? w2 : w3;
        float f = src[g & 4095];
        ushort h = f2bf(f);
        hi[g] = h;
        lo[g] = f2bf(f - bf2f(h));
    }
}

// ---------------------------------------------------------------------------
// aggregate: wave per node; half-wave per neighbor row (bf16, 128 B/row).
// lane = 2 features (2i, 2i+1); neighbor indices prefetched into cid and
// broadcast with shfl; 8 row-loads in flight per wave. Writes mean as bf16.
// ---------------------------------------------------------------------------
__global__ __launch_bounds__(256) void aggregate(const uint* __restrict__ xb,
                                                 const int* __restrict__ col,
                                                 const int* __restrict__ offs,
                                                 uint* __restrict__ meanb) {
    const int lane = threadIdx.x & 63;
    const int i    = lane & 31;      // feature pair index
    const int half = lane >> 5;      // which neighbor of the pair
    const int wid  = (blockIdx.x * 256 + threadIdx.x) >> 6;
    const int nw   = gridDim.x * 4;

    for (int node = wid; node < NN; node += nw) {
        const int un  = __builtin_amdgcn_readfirstlane(node);
        const int off = offs[un];
        const int end = (un + 1 < NN) ? offs[un + 1] : NE;
        const int deg = end - off;

        float a0 = 0.f, a1 = 0.f;
        int cid = (lane < deg) ? col[off + lane] : 0;   // first 64 neighbor ids
        const int npf = min((deg + 1) >> 1, 32);        // pairs in fast path

        for (int p0 = 0; p0 < npf; p0 += 8) {
            uint w[8];
            int  kk[8];
            #pragma unroll
            for (int u = 0; u < 8; ++u) {
                int k = ((p0 + u) << 1) + half;         // k < 64 in fast path
                kk[u] = k;
                int e = __shfl(cid, k & 63);
                w[u] = xb[e * 32 + i];
            }
            #pragma unroll
            for (int u = 0; u < 8; ++u) {
                if (kk[u] < deg) { a0 += bflo_f(w[u]); a1 += bfhi_f(w[u]); }
            }
        }
        for (int k = 64 + half; k < deg; k += 2) {      // rare deg>64 tail
            int e = col[off + k];
            uint w = xb[e * 32 + i];
            a0 += bflo_f(w); a1 += bfhi_f(w);
        }
        a0 += __shfl_xor(a0, 32);
        a1 += __shfl_xor(a1, 32);
        const float inv = 1.0f / (float)max(deg, 1);
        if (half == 0)
            meanb[(size_t)un * 32 + i] =
                (uint)f2bf(a0 * inv) | ((uint)f2bf(a1 * inv) << 16);
    }
}

// ---------------------------------------------------------------------------
// combine GEMM: out[m][n] = mean[m]@Wl^T + self[m]@Wr^T + b (+relu)
// wave per 16-node M-tile; mfma_f32_16x16x32_bf16.
// A frag: row = lane&15, k = (lane>>4)*8 + j (contiguous 16B load)
// B frag: col = lane&15, k = (lane>>4)*8 + j -> W[n][k] row-major 16B load
// C/D:    col(n) = lane&15, row(m) = (lane>>4)*4 + reg   [m89-verified]
// Precision: W split hi/lo; fp32 self split hi/lo -> only mean path carries
// bf16 gather error.
// ---------------------------------------------------------------------------
template<int SELF_BF16, int WF32, int WB16>
__global__ __launch_bounds__(256) void gemm_combine(
        const ushort* __restrict__ meanb,
        const float*  __restrict__ selff,
        const ushort* __restrict__ selfb,
        const ushort* __restrict__ wl_hi, const ushort* __restrict__ wl_lo,
        const ushort* __restrict__ wr_hi, const ushort* __restrict__ wr_lo,
        const float*  __restrict__ bias,
        float* __restrict__ outf, ushort* __restrict__ outb,
        int do_relu)
{
    const int l    = threadIdx.x & 63;
    const int wid  = (blockIdx.x * 256 + threadIdx.x) >> 6;
    const int nw   = gridDim.x * 4;
    const int m16  = l & 15;
    const int koff = (l >> 4) * 8;
    const int NT   = NN / 16;      // 6250

    for (int tile = wid; tile < NT; tile += nw) {
        const int mbase = tile * 16;

        short8v am[2], ashi[2], aslo[2];
        #pragma unroll
        for (int kk = 0; kk < 2; ++kk) {
            const size_t ro = (size_t)(mbase + m16) * 64 + kk * 32 + koff;
            am[kk] = *(const short8v*)(meanb + ro);
            if (SELF_BF16) {
                ashi[kk] = *(const short8v*)(selfb + ro);
            } else {
                const float4* xp = (const float4*)(selff + ro);
                float4 v0 = xp[0], v1 = xp[1];
                float vv[8] = {v0.x, v0.y, v0.z, v0.w, v1.x, v1.y, v1.z, v1.w};
                short8v h, lo2;
                #pragma unroll
                for (int j = 0; j < 8; ++j) {
                    ushort hb_ = f2bf(vv[j]);
                    h[j]  = (short)hb_;
                    lo2[j] = (short)f2bf(vv[j] - bf2f(hb_));
                }
                ashi[kk] = h;
                aslo[kk] = lo2;
            }
        }

        #pragma unroll
        for (int nt = 0; nt < 4; ++nt) {
            f32x4 acc = {0.f, 0.f, 0.f, 0.f};
            #pragma unroll
            for (int kk = 0; kk < 2; ++kk) {
                const size_t wo = (size_t)(nt * 16 + m16) * 64 + kk * 32 + koff;
                short8v bwlh = *(const short8v*)(wl_hi + wo);
                short8v bwll = *(const short8v*)(wl_lo + wo);
                short8v bwrh = *(const short8v*)(wr_hi + wo);
                short8v bwrl = *(const short8v*)(wr_lo + wo);
                acc = __builtin_amdgcn_mfma_f32_16x16x32_bf16(am[kk],  bwlh, acc, 0, 0, 0);
                acc = __builtin_amdgcn_mfma_f32_16x16x32_bf16(am[kk],  bwll, acc, 0, 0, 0);
                acc = __builtin_amdgcn_mfma_f32_16x16x32_bf16(ashi[kk], bwrh, acc, 0, 0, 0);
                if (!SELF_BF16)
                    acc = __builtin_amdgcn_mfma_f32_16x16x32_bf16(aslo[kk], bwrh, acc, 0, 0, 0);
                acc = __builtin_amdgcn_mfma_f32_16x16x32_bf16(ashi[kk], bwrl, acc, 0, 0, 0);
            }
            const float bv = bias[nt * 16 + m16];
            #pragma unroll
            for (int r = 0; r < 4; ++r) {
                float v = acc[r] + bv;
                if (do_relu) v = fmaxf(v, 0.f);
                const size_t oi = (size_t)(mbase + (l >> 4) * 4 + r) * 64 + nt * 16 + m16;
                if (WF32) outf[oi] = v;
                if (WB16) outb[oi] = f2bf(v);
            }
        }
    }
}

// ---------------------------------------------------------------------------
extern "C" void kernel_launch(void* const* d_in, const int* in_sizes, int n_in,
                              void* d_out, int out_size, void* d_ws, size_t ws_size,
                              hipStream_t stream) {
    const float* x   = (const float*)d_in[0];
    const int*   ei  = (const int*)d_in[1];     // [2, NE] int32
    const float* W1l = (const float*)d_in[2];
    const float* b1  = (const float*)d_in[3];
    const float* W1r = (const float*)d_in[4];
    const float* W2l = (const float*)d_in[5];
    const float* b2  = (const float*)d_in[6];
    const float* W2r = (const float*)d_in[7];
    float*       out = (float*)d_out;

    const int* src = ei;
    const int* dst = ei + NE;

    // ---- workspace layout ----
    char* p = (char*)d_ws;
    int*    col   = (int*)p;     p += (size_t)NE * 4;          // 5.12 MB
    int*    offs  = (int*)p;     p += (size_t)NN * 4;          // 0.4 MB
    int*    cnt   = (int*)p;     p += (size_t)NN * 4;          // 0.4 MB
    int*    part  = (int*)p;     p += 4096;
    ushort* whi   = (ushort*)p;  p += (size_t)4 * 4096 * 2;    // 32 KB
    ushort* wlo   = (ushort*)p;  p += (size_t)4 * 4096 * 2;    // 32 KB
    uint*   xb    = (uint*)p;    p += (size_t)NN * 32 * 4;     // 12.8 MB (reused as hb)
    uint*   meanb = (uint*)p;    p += (size_t)NN * 32 * 4;     // 12.8 MB
    // big-ws only: fp32 h
    float*  hf    = (float*)p;                                 // +25.6 MB
    const bool big = ws_size >= (size_t)(p - (char*)d_ws) + (size_t)NN * D * 4;

    // weight order in whi/wlo: 0=W1l, 1=W1r, 2=W2l, 3=W2r
    const ushort* w1l_hi = whi;             const ushort* w1l_lo = wlo;
    const ushort* w1r_hi = whi + 4096;      const ushort* w1r_lo = wlo + 4096;
    const ushort* w2l_hi = whi + 2 * 4096;  const ushort* w2l_lo = wlo + 2 * 4096;
    const ushort* w2r_hi = whi + 3 * 4096;  const ushort* w2r_lo = wlo + 3 * 4096;

    hipMemsetAsync(cnt, 0, (size_t)NN * 4, stream);

    // ---- prep (independent of CSR) ----
    prep_x<<<(NN * 32 + 255) / 256, 256, 0, stream>>>(x, xb);
    prep_w<<<(4 * 4096 + 255) / 256, 256, 0, stream>>>(W1l, W1r, W2l, W2r, whi, wlo);

    // ---- CSR build ----
    count_kernel<<<(NE + 255) / 256, 256, 0, stream>>>(dst, cnt);
    scanA<<<NPART, 256, 0, stream>>>(cnt, offs, part);
    scanB<<<1, 512, 0, stream>>>(part);
    scanC<<<NPART, 256, 0, stream>>>(offs, part);
    bucket_kernel<<<(NE + 255) / 256, 256, 0, stream>>>(src, dst, offs, cnt, col);

    // ---- layer 1 ----
    aggregate<<<2048, 256, 0, stream>>>(xb, col, offs, meanb);
    if (big) {
        gemm_combine<0, 1, 1><<<1024, 256, 0, stream>>>(
            (const ushort*)meanb, x, nullptr,
            w1l_hi, w1l_lo, w1r_hi, w1r_lo, b1, hf, (ushort*)xb, 1);
    } else {
        gemm_combine<0, 0, 1><<<1024, 256, 0, stream>>>(
            (const ushort*)meanb, x, nullptr,
            w1l_hi, w1l_lo, w1r_hi, w1r_lo, b1, nullptr, (ushort*)xb, 1);
    }

    // ---- layer 2 (hb lives in xb region) ----
    aggregate<<<2048, 256, 0, stream>>>(xb, col, offs, meanb);
    if (big) {
        gemm_combine<0, 1, 0><<<1024, 256, 0, stream>>>(
            (const ushort*)meanb, hf, nullptr,
            w2l_hi, w2l_lo, w2r_hi, w2r_lo, b2, out, nullptr, 0);
    } else {
        gemm_combine<1, 1, 0><<<1024, 256, 0, stream>>>(
            (const ushort*)meanb, nullptr, (const ushort*)xb,
            w2l_hi, w2l_lo, w2r_hi, w2r_lo, b2, out, nullptr, 0);
    }
}